// Round 15
// baseline (752.188 us; speedup 1.0000x reference)
//
#include <hip/hip_runtime.h>
#include <hip/hip_bf16.h>

#define N_NODES 100000
#define E_EDGES 1600000
#define IN_DIM  256
#define HID     128
#define OUT_DIM 64
#define LAYERS  3
#define LN_EPS  1e-5f

typedef __attribute__((ext_vector_type(8)))  short bf16x8;   // 8 bf16 = 4 VGPRs
typedef __attribute__((ext_vector_type(16))) float f32x16;   // MFMA 32x32 accumulator

__device__ inline short f2bf(float f) {              // round-to-nearest-even
    unsigned u = __float_as_uint(f);
    unsigned r = (u + 0x7fffu + ((u >> 16) & 1u)) >> 16;
    return (short)r;
}
__device__ inline float bflo(unsigned u) { return __uint_as_float(u << 16); }
__device__ inline float bfhi(unsigned u) { return __uint_as_float(u & 0xffff0000u); }

// ---------------- degree / dinv ----------------

__global__ __launch_bounds__(256) void deg_kernel(const int* __restrict__ dst, int* __restrict__ deg) {
    int e = blockIdx.x * 256 + threadIdx.x;
    if (e < E_EDGES) atomicAdd(&deg[dst[e]], 1);
}

__global__ __launch_bounds__(256) void dinv_kernel(const int* __restrict__ deg, float* __restrict__ dinv) {
    int i = blockIdx.x * 256 + threadIdx.x;
    if (i < N_NODES) dinv[i] = rsqrtf((float)(deg[i] + 1));  // +1 = self loop
}

// ---------------- CSR build ----------------

#define NB_SCAN ((N_NODES + 255) / 256)   // 391

__global__ __launch_bounds__(256) void block_sum_kernel(const int* __restrict__ deg,
                                                        int* __restrict__ blockSums) {
    __shared__ int s[256];
    int i = blockIdx.x * 256 + threadIdx.x;
    s[threadIdx.x] = (i < N_NODES) ? deg[i] : 0;
    __syncthreads();
#pragma unroll
    for (int o = 128; o; o >>= 1) {
        if (threadIdx.x < o) s[threadIdx.x] += s[threadIdx.x + o];
        __syncthreads();
    }
    if (threadIdx.x == 0) blockSums[blockIdx.x] = s[0];
}

__global__ __launch_bounds__(512) void scan_blocks_kernel(int* __restrict__ blockSums, int nb) {
    __shared__ int s[512];
    int t = threadIdx.x;
    int orig = (t < nb) ? blockSums[t] : 0;
    s[t] = orig;
    __syncthreads();
#pragma unroll
    for (int o = 1; o < 512; o <<= 1) {
        int v = (t >= o) ? s[t - o] : 0;
        __syncthreads();
        s[t] += v;
        __syncthreads();
    }
    if (t < nb) blockSums[t] = s[t] - orig;   // exclusive
}

__global__ __launch_bounds__(256) void scan_final_kernel(const int* __restrict__ deg,
                                                         const int* __restrict__ blockSums,
                                                         int* __restrict__ offsets,
                                                         int* __restrict__ cursor) {
    __shared__ int s[256];
    int i = blockIdx.x * 256 + threadIdx.x;
    int t = threadIdx.x;
    int v = (i < N_NODES) ? deg[i] : 0;
    s[t] = v;
    __syncthreads();
#pragma unroll
    for (int o = 1; o < 256; o <<= 1) {
        int u = (t >= o) ? s[t - o] : 0;
        __syncthreads();
        s[t] += u;
        __syncthreads();
    }
    if (i < N_NODES) {
        int excl = s[t] - v + blockSums[blockIdx.x];
        offsets[i] = excl;
        cursor[i] = excl;
    }
}

// es stores ONLY src (4B): per-edge weight is folded into xwb scaling (src
// side, conv GEMM epilogue) and the gather's final dinv[dst] scale.
__global__ __launch_bounds__(256) void bin_kernel(const int* __restrict__ src,
                                                  const int* __restrict__ dst,
                                                  int* __restrict__ cursor,
                                                  int* __restrict__ es) {
    int e = blockIdx.x * 256 + threadIdx.x;
    if (e >= E_EDGES) return;
    int s = src[e], d = dst[e];
    int p = atomicAdd(&cursor[d], 1);
    es[p] = s;
}

// ---------------- weight transpose+cast: WT[n][k] (bf16) from W[k][n] (f32) ----------------

template<int K, int N>
__global__ __launch_bounds__(256) void wt_kernel(const float* __restrict__ W, short* __restrict__ WT) {
    int idx = blockIdx.x * 256 + threadIdx.x;
    if (idx >= K * N) return;
    int n = idx / K, k = idx % K;
    WT[idx] = f2bf(W[(long)k * N + n]);
}

// ---------------- MFMA bf16 GEMM: C[M,N] = A[M,KT] @ W[KT,N] (+bias, +row scale) ----------------
// No LDS, no barriers. WT is L2/L3-resident; broadcast-read per fragment.
// Wave owns a 32xN tile; named double-buffer prefetch; launch_bounds(256,3).
// scale (per-row, e.g. dinv) multiplies stored values (used by conv GEMM).
// v_mfma_f32_32x32x16_bf16 C layout: col=lane&31, row=(reg&3)+8*(reg>>2)+4*(lane>>5)

template<int KT, int N, bool ABF>
__global__ __launch_bounds__(256, 3) void mfma_gemm(const void* __restrict__ Av,
                                                    const short* __restrict__ WT,
                                                    const float* __restrict__ bias,
                                                    const float* __restrict__ scale,
                                                    float* __restrict__ C,
                                                    short* __restrict__ Cb,
                                                    int M) {
    constexpr int NT = N / 32;
    constexpr int KTS = KT / 16;

    const int tid = threadIdx.x;
    const int wv = tid >> 6;
    const int ln = tid & 63;
    const int l31 = ln & 31;
    const int lh = ln >> 5;
    const int row0 = blockIdx.x * 128 + wv * 32;

    int ar = row0 + l31;
    if (ar > M - 1) ar = M - 1;                  // clamp; store is guarded

    const short* abf = (const short*)Av + (long)ar * KT + lh * 8;
    const float* af32 = (const float*)Av + (long)ar * KT + lh * 8;
    const short* bbase[NT];
#pragma unroll
    for (int nt = 0; nt < NT; nt++)
        bbase[nt] = WT + (long)(nt * 32 + l31) * KT + lh * 8;

    f32x16 acc[NT];
#pragma unroll
    for (int nt = 0; nt < NT; nt++)
#pragma unroll
        for (int r = 0; r < 16; r++) acc[nt][r] = 0.f;

    auto loadA = [&](int ks) -> bf16x8 {
        if (ABF) {
            return *(const bf16x8*)(abf + ks * 16);
        } else {
            float4 f0 = *(const float4*)(af32 + ks * 16);
            float4 f1 = *(const float4*)(af32 + ks * 16 + 4);
            bf16x8 t;
            t[0] = f2bf(f0.x); t[1] = f2bf(f0.y); t[2] = f2bf(f0.z); t[3] = f2bf(f0.w);
            t[4] = f2bf(f1.x); t[5] = f2bf(f1.y); t[6] = f2bf(f1.z); t[7] = f2bf(f1.w);
            return t;
        }
    };

    bf16x8 a_cur, a_nxt;
    bf16x8 b_cur[NT], b_nxt[NT];

    a_cur = loadA(0);
#pragma unroll
    for (int nt = 0; nt < NT; nt++) b_cur[nt] = *(const bf16x8*)(bbase[nt]);

#pragma unroll
    for (int ks = 0; ks < KTS; ks++) {
        if (ks + 1 < KTS) {
            a_nxt = loadA(ks + 1);
#pragma unroll
            for (int nt = 0; nt < NT; nt++)
                b_nxt[nt] = *(const bf16x8*)(bbase[nt] + (ks + 1) * 16);
        }
#pragma unroll
        for (int nt = 0; nt < NT; nt++)
            acc[nt] = __builtin_amdgcn_mfma_f32_32x32x16_bf16(a_cur, b_cur[nt], acc[nt], 0, 0, 0);
        if (ks + 1 < KTS) {
            a_cur = a_nxt;
#pragma unroll
            for (int nt = 0; nt < NT; nt++) b_cur[nt] = b_nxt[nt];
        }
    }

    // epilogue: outer loop over the 16 C rows, inner over col tiles
#pragma unroll
    for (int r = 0; r < 16; r++) {
        int row = row0 + (r & 3) + 8 * (r >> 2) + 4 * lh;
        if (row >= M) continue;
        float sc = scale ? scale[row] : 1.0f;
#pragma unroll
        for (int nt = 0; nt < NT; nt++) {
            int col = nt * 32 + l31;
            float v = acc[nt][r] + (bias ? bias[col] : 0.0f);
            v *= sc;
            if (C)  C[(long)row * N + col] = v;
            if (Cb) Cb[(long)row * N + col] = f2bf(v);
        }
    }
}

// ---------------- fused gather + selfloop + bias + LN + relu + residual ----------------
// one wave per node, 2 features per lane. xwb holds xs = dinv[src]*xw (bf16);
// y = dinv[dst] * (sum_edges xs[src] + xs[dst]) + bias. 8-deep gather unroll.

__global__ __launch_bounds__(256) void gather_post_kernel(const int* __restrict__ offsets,
                                                          const int* __restrict__ deg,
                                                          const int* __restrict__ es,
                                                          const float* __restrict__ dinv,
                                                          const short* __restrict__ xwb,
                                                          const float* __restrict__ b,
                                                          const float* __restrict__ g,
                                                          const float* __restrict__ beta,
                                                          float* __restrict__ h,
                                                          short* __restrict__ hb) {
    int wave = threadIdx.x >> 6;
    int lane = threadIdx.x & 63;
    int row = blockIdx.x * 4 + wave;
    if (row >= N_NODES) return;

    const int* ep = es + offsets[row];
    int dg = deg[row];

    float acc0 = 0.f, acc1 = 0.f;
    int j = 0;
    for (; j + 8 <= dg; j += 8) {
        int s0 = ep[j + 0], s1 = ep[j + 1], s2 = ep[j + 2], s3 = ep[j + 3];
        int s4 = ep[j + 4], s5 = ep[j + 5], s6 = ep[j + 6], s7 = ep[j + 7];
        unsigned u0 = *(const unsigned*)(&xwb[(long)s0 * HID + lane * 2]);
        unsigned u1 = *(const unsigned*)(&xwb[(long)s1 * HID + lane * 2]);
        unsigned u2 = *(const unsigned*)(&xwb[(long)s2 * HID + lane * 2]);
        unsigned u3 = *(const unsigned*)(&xwb[(long)s3 * HID + lane * 2]);
        unsigned u4 = *(const unsigned*)(&xwb[(long)s4 * HID + lane * 2]);
        unsigned u5 = *(const unsigned*)(&xwb[(long)s5 * HID + lane * 2]);
        unsigned u6 = *(const unsigned*)(&xwb[(long)s6 * HID + lane * 2]);
        unsigned u7 = *(const unsigned*)(&xwb[(long)s7 * HID + lane * 2]);
        acc0 += bflo(u0); acc1 += bfhi(u0);
        acc0 += bflo(u1); acc1 += bfhi(u1);
        acc0 += bflo(u2); acc1 += bfhi(u2);
        acc0 += bflo(u3); acc1 += bfhi(u3);
        acc0 += bflo(u4); acc1 += bfhi(u4);
        acc0 += bflo(u5); acc1 += bfhi(u5);
        acc0 += bflo(u6); acc1 += bfhi(u6);
        acc0 += bflo(u7); acc1 += bfhi(u7);
    }
    if (j + 4 <= dg) {
        int s0 = ep[j + 0], s1 = ep[j + 1], s2 = ep[j + 2], s3 = ep[j + 3];
        unsigned u0 = *(const unsigned*)(&xwb[(long)s0 * HID + lane * 2]);
        unsigned u1 = *(const unsigned*)(&xwb[(long)s1 * HID + lane * 2]);
        unsigned u2 = *(const unsigned*)(&xwb[(long)s2 * HID + lane * 2]);
        unsigned u3 = *(const unsigned*)(&xwb[(long)s3 * HID + lane * 2]);
        acc0 += bflo(u0); acc1 += bfhi(u0);
        acc0 += bflo(u1); acc1 += bfhi(u1);
        acc0 += bflo(u2); acc1 += bfhi(u2);
        acc0 += bflo(u3); acc1 += bfhi(u3);
        j += 4;
    }
    for (; j < dg; j++) {
        int s0 = ep[j];
        unsigned u0 = *(const unsigned*)(&xwb[(long)s0 * HID + lane * 2]);
        acc0 += bflo(u0); acc1 += bfhi(u0);
    }

    float di = dinv[row];
    unsigned ux = *(const unsigned*)(&xwb[(long)row * HID + lane * 2]);  // xs[row]
    float2 bv = *reinterpret_cast<const float2*>(&b[lane * 2]);
    float y0 = (acc0 + bflo(ux)) * di + bv.x;
    float y1 = (acc1 + bfhi(ux)) * di + bv.y;

    float sum = y0 + y1;
#pragma unroll
    for (int o = 32; o; o >>= 1) sum += __shfl_xor(sum, o);
    float mu = sum * (1.0f / HID);

    float d0 = y0 - mu, d1 = y1 - mu;
    float vs = d0 * d0 + d1 * d1;
#pragma unroll
    for (int o = 32; o; o >>= 1) vs += __shfl_xor(vs, o);
    float rstd = rsqrtf(vs * (1.0f / HID) + LN_EPS);

    float2 gv = *reinterpret_cast<const float2*>(&g[lane * 2]);
    float2 bev = *reinterpret_cast<const float2*>(&beta[lane * 2]);
    float r0 = fmaxf(d0 * rstd * gv.x + bev.x, 0.0f);
    float r1 = fmaxf(d1 * rstd * gv.y + bev.y, 0.0f);

    float2* hp = reinterpret_cast<float2*>(&h[(long)row * HID + lane * 2]);
    float2 hv = *hp;
    hv.x += r0;
    hv.y += r1;
    *hp = hv;

    unsigned pk = ((unsigned)(unsigned short)f2bf(hv.y) << 16) |
                  (unsigned)(unsigned short)f2bf(hv.x);
    *reinterpret_cast<unsigned*>(&hb[(long)row * HID + lane * 2]) = pk;
}

// ---------------- launch ----------------

extern "C" void kernel_launch(void* const* d_in, const int* in_sizes, int n_in,
                              void* d_out, int out_size, void* d_ws, size_t ws_size,
                              hipStream_t stream) {
    const float* x      = (const float*)d_in[0];
    const int*   eidx   = (const int*)d_in[1];
    const float* in_W   = (const float*)d_in[2];
    const float* in_b   = (const float*)d_in[3];
    const float* conv_W = (const float*)d_in[4];
    const float* conv_b = (const float*)d_in[5];
    const float* ln_g   = (const float*)d_in[6];
    const float* ln_b   = (const float*)d_in[7];
    const float* out_W  = (const float*)d_in[8];
    const float* out_b  = (const float*)d_in[9];

    const int* src = eidx;
    const int* dst = eidx + E_EDGES;

    char* ws = (char*)d_ws;
    size_t off = 0;
    auto alloc = [&](size_t bytes) {
        void* p = ws + off;
        off += (bytes + 1023) & ~(size_t)1023;
        return p;
    };
    int*   deg       = (int*)  alloc((size_t)N_NODES * 4);
    float* dinv      = (float*)alloc((size_t)N_NODES * 4);
    int*   offsets   = (int*)  alloc((size_t)N_NODES * 4);
    int*   cursor    = (int*)  alloc((size_t)N_NODES * 4);
    int*   blockSums = (int*)  alloc((size_t)NB_SCAN * 4);
    int*   es        = (int*)  alloc((size_t)E_EDGES * 4);
    float* h         = (float*)alloc((size_t)N_NODES * HID * 4);
    short* hb        = (short*)alloc((size_t)N_NODES * HID * 2);
    short* xwb       = (short*)alloc((size_t)N_NODES * HID * 2);
    short* in_WT     = (short*)alloc((size_t)IN_DIM * HID * 2);
    short* conv_WT   = (short*)alloc((size_t)LAYERS * HID * HID * 2);
    short* out_WT    = (short*)alloc((size_t)HID * OUT_DIM * 2);

    hipMemsetAsync(deg, 0, (size_t)N_NODES * 4, stream);
    deg_kernel<<<(E_EDGES + 255) / 256, 256, 0, stream>>>(dst, deg);
    dinv_kernel<<<(N_NODES + 255) / 256, 256, 0, stream>>>(deg, dinv);

    // CSR build
    block_sum_kernel<<<NB_SCAN, 256, 0, stream>>>(deg, blockSums);
    scan_blocks_kernel<<<1, 512, 0, stream>>>(blockSums, NB_SCAN);
    scan_final_kernel<<<NB_SCAN, 256, 0, stream>>>(deg, blockSums, offsets, cursor);
    bin_kernel<<<(E_EDGES + 255) / 256, 256, 0, stream>>>(src, dst, cursor, es);

    // weight cast+transpose
    wt_kernel<IN_DIM, HID><<<(IN_DIM * HID + 255) / 256, 256, 0, stream>>>(in_W, in_WT);
    for (int l = 0; l < LAYERS; l++)
        wt_kernel<HID, HID><<<(HID * HID + 255) / 256, 256, 0, stream>>>(
            conv_W + (size_t)l * HID * HID, conv_WT + (size_t)l * HID * HID);
    wt_kernel<HID, OUT_DIM><<<(HID * OUT_DIM + 255) / 256, 256, 0, stream>>>(out_W, out_WT);

    const int ggrid = (N_NODES + 127) / 128;   // 782

    // h = x @ in_W + in_b   (A = f32 x, converted in-flight)
    mfma_gemm<IN_DIM, HID, false><<<ggrid, 256, 0, stream>>>(
        (const void*)x, in_WT, in_b, nullptr, h, hb, N_NODES);

    for (int l = 0; l < LAYERS; l++) {
        // xwb = dinv * (hb @ conv_W)   (bf16, src-side norm folded in)
        mfma_gemm<HID, HID, true><<<ggrid, 256, 0, stream>>>(
            (const void*)hb, conv_WT + (size_t)l * HID * HID, nullptr, dinv, nullptr, xwb, N_NODES);
        gather_post_kernel<<<(N_NODES + 3) / 4, 256, 0, stream>>>(
            offsets, deg, es, dinv, xwb,
            conv_b + l * HID, ln_g + l * HID, ln_b + l * HID, h, hb);
    }

    mfma_gemm<HID, OUT_DIM, true><<<ggrid, 256, 0, stream>>>(
        (const void*)hb, out_WT, out_b, nullptr, (float*)d_out, nullptr, N_NODES);
}